// Round 1
// baseline (435.434 us; speedup 1.0000x reference)
//
#include <hip/hip_runtime.h>
#include <hip/hip_bf16.h>

// Problem: B=128, N=196, C=768, centers=64
//   q = mean_n x; attn = softmax(l2n(q)@l2n(k_c) * C^-0.5)
//   v = attn@v_c (B,N,N); out = (v @ x) @ W^T + b
// Reassociated: xp_t[b,d,m] = sum_k W[d,k] x[b,m,k]  (NT GEMM, output transposed)
//               out[b,n,d]  = sum_m v[b,n,m] xp_t[b,d,m] + bias[d] (NT GEMM)
// Padding: K dims padded 196->224 (7x32) with zeros; operand-row dims padded to
// 256 so 128-wide tiles never read OOB. All pads are written every launch
// (ws is re-poisoned 0xAA before each timed call).

#define NB   128
#define NN   196
#define NC   768
#define NCEN 64
#define RPAD 256   // padded row-dim for x_bf (m rows) and v_pad (n rows)
#define KPAD 224   // padded K dim (m index), 7*32

using bf16x8 = __attribute__((ext_vector_type(8))) short;
using f32x4  = __attribute__((ext_vector_type(4))) float;

// ---------------- kernel 1: x -> bf16 (padded) + column means q ----------------
__global__ __launch_bounds__(256)
void convert_x_kernel(const float* __restrict__ x, __hip_bfloat16* __restrict__ x_bf,
                      float* __restrict__ q) {
    int b = blockIdx.x, chunk = blockIdx.y, t = threadIdx.x;
    int c = chunk * 256 + t;
    const float* xp = x + (size_t)b * NN * NC + c;
    __hip_bfloat16* xo = x_bf + (size_t)b * RPAD * NC + c;
    float s = 0.f;
    for (int m = 0; m < NN; ++m) {
        float v = xp[(size_t)m * NC];
        s += v;
        xo[(size_t)m * NC] = __float2bfloat16(v);
    }
    __hip_bfloat16 z = __float2bfloat16(0.f);
    for (int m = NN; m < RPAD; ++m) xo[(size_t)m * NC] = z;
    q[b * NC + c] = s * (1.0f / (float)NN);
}

// ---------------- kernel 2: proj_w -> bf16 ----------------
__global__ __launch_bounds__(256)
void convert_w_kernel(const float* __restrict__ w, __hip_bfloat16* __restrict__ w_bf) {
    int i = blockIdx.x * 256 + threadIdx.x;
    if (i < NC * NC) w_bf[i] = __float2bfloat16(w[i]);
}

// ---------------- kernel 3: attn = softmax(l2n(q) @ l2n(k_c) * scale) ----------------
__global__ __launch_bounds__(256)
void attn_kernel(const float* __restrict__ q, const float* __restrict__ k_c,
                 float* __restrict__ attn) {
    const float SCALE = 0.03608439182435161f;  // 768^-0.5
    int b = blockIdx.x, t = threadIdx.x;
    __shared__ float qs[NC];
    __shared__ float red[256];
    __shared__ float pd[4][NCEN];
    __shared__ float pk[4][NCEN];

    for (int i = t; i < NC; i += 256) qs[i] = q[b * NC + i];
    __syncthreads();

    float s = 0.f;
    for (int i = t; i < NC; i += 256) { float v = qs[i]; s += v * v; }
    red[t] = s;
    __syncthreads();
    for (int o = 128; o > 0; o >>= 1) {
        if (t < o) red[t] += red[t + o];
        __syncthreads();
    }
    float qn = sqrtf(red[0]);

    int j = t & 63, part = t >> 6;  // 4 parts x 192 c's
    float d = 0.f, kk = 0.f;
    int c0 = part * 192;
    for (int c = c0; c < c0 + 192; ++c) {
        float kv = k_c[c * NCEN + j];
        d += kv * qs[c];
        kk += kv * kv;
    }
    pd[part][j] = d;
    pk[part][j] = kk;
    __syncthreads();

    if (t < NCEN) {
        float dot = pd[0][t] + pd[1][t] + pd[2][t] + pd[3][t];
        float kn  = sqrtf(pk[0][t] + pk[1][t] + pk[2][t] + pk[3][t]);
        float lg = dot / (fmaxf(qn, 1e-12f) * fmaxf(kn, 1e-12f)) * SCALE;
        float mx = lg;
        for (int o = 32; o > 0; o >>= 1) mx = fmaxf(mx, __shfl_xor(mx, o, 64));
        float e = expf(lg - mx);
        float sum = e;
        for (int o = 32; o > 0; o >>= 1) sum += __shfl_xor(sum, o, 64);
        attn[b * NCEN + t] = e / sum;
    }
}

// ---------------- kernel 4: v_pad[b,n,m] = sum_c attn[b,c] v_c[c,n,m] (bf16, padded) ----------------
__global__ __launch_bounds__(256)
void mix_kernel(const float* __restrict__ attn, const float* __restrict__ v_c,
                __hip_bfloat16* __restrict__ v_pad) {
    int n = blockIdx.x;   // 0..255
    int m = threadIdx.x;  // 0..255, active < 224
    if (m >= KPAD) return;
    __hip_bfloat16 z = __float2bfloat16(0.f);
    if (n >= NN || m >= NN) {
        for (int b = 0; b < NB; ++b)
            v_pad[(size_t)b * RPAD * KPAD + (size_t)n * KPAD + m] = z;
        return;
    }
    float vc[NCEN];
    const float* vp = v_c + (size_t)n * NN + m;
#pragma unroll
    for (int c = 0; c < NCEN; ++c) vc[c] = vp[(size_t)c * NN * NN];
    for (int b = 0; b < NB; ++b) {
        const float* ab = attn + b * NCEN;
        float acc = 0.f;
#pragma unroll
        for (int c = 0; c < NCEN; ++c) acc += ab[c] * vc[c];
        v_pad[(size_t)b * RPAD * KPAD + (size_t)n * KPAD + m] = __float2bfloat16(acc);
    }
}

// ---------------- NT GEMM: C[row,col] = sum_k A[row,k] * B[col,k] (+bias[col]) ----------------
// 128x128 tile, BK=32, 4 waves, each wave 64x64 via 4x4 mfma_f32_16x16x32_bf16.
// LDS row stride padded to 40 shorts to break bank conflicts.
template <bool OUT_BF16>
__global__ __launch_bounds__(256)
void gemm_nt(const __hip_bfloat16* __restrict__ A, size_t strideA,
             const __hip_bfloat16* __restrict__ Bm, size_t strideB,
             void* __restrict__ Cout, size_t strideC,
             const float* __restrict__ bias,
             int lda, int ldb, int ldc, int K, int Mstore, int Nstore) {
    int bm = blockIdx.x, bn = blockIdx.y, bb = blockIdx.z;
    const unsigned short* Ab = (const unsigned short*)A + (size_t)bb * strideA + (size_t)bm * 128 * lda;
    const unsigned short* Bb = (const unsigned short*)Bm + (size_t)bb * strideB + (size_t)bn * 128 * ldb;

    __shared__ __align__(16) unsigned short sA[128 * 40];
    __shared__ __align__(16) unsigned short sB[128 * 40];

    int tid = threadIdx.x;
    int wave = tid >> 6, lane = tid & 63;
    int wr = wave >> 1, wc = wave & 1;
    int lrow = lane & 15, quad = lane >> 4;

    f32x4 acc[4][4] = {};

    for (int k0 = 0; k0 < K; k0 += 32) {
        __syncthreads();
        // stage 128x32 bf16 A and B tiles: 512 chunks of 16B, 2 per thread
#pragma unroll
        for (int i = 0; i < 2; ++i) {
            int ci = tid + i * 256;
            int row = ci >> 2, cp = ci & 3;
            uint4 va = *(const uint4*)(Ab + (size_t)row * lda + k0 + cp * 8);
            *(uint4*)(&sA[row * 40 + cp * 8]) = va;
            uint4 vb = *(const uint4*)(Bb + (size_t)row * ldb + k0 + cp * 8);
            *(uint4*)(&sB[row * 40 + cp * 8]) = vb;
        }
        __syncthreads();

        bf16x8 af[4], bf[4];
#pragma unroll
        for (int i = 0; i < 4; ++i)
            af[i] = *(const bf16x8*)(&sA[(wr * 64 + i * 16 + lrow) * 40 + quad * 8]);
#pragma unroll
        for (int j = 0; j < 4; ++j)
            bf[j] = *(const bf16x8*)(&sB[(wc * 64 + j * 16 + lrow) * 40 + quad * 8]);
#pragma unroll
        for (int i = 0; i < 4; ++i)
#pragma unroll
            for (int j = 0; j < 4; ++j)
                acc[i][j] = __builtin_amdgcn_mfma_f32_16x16x32_bf16(af[i], bf[j], acc[i][j], 0, 0, 0);
    }

    // epilogue: D[row=(lane>>4)*4+r][col=lane&15] per 16x16 tile (m89-verified mapping)
    size_t cbase = (size_t)bb * strideC;
#pragma unroll
    for (int i = 0; i < 4; ++i) {
        int row0 = bm * 128 + wr * 64 + i * 16 + quad * 4;
#pragma unroll
        for (int j = 0; j < 4; ++j) {
            int col = bn * 128 + wc * 64 + j * 16 + lrow;
            if (col < Nstore) {
                float badd = bias ? bias[col] : 0.f;
#pragma unroll
                for (int r = 0; r < 4; ++r) {
                    int row = row0 + r;
                    if (row < Mstore) {
                        float v = acc[i][j][r] + badd;
                        if (OUT_BF16)
                            ((__hip_bfloat16*)Cout)[cbase + (size_t)row * ldc + col] = __float2bfloat16(v);
                        else
                            ((float*)Cout)[cbase + (size_t)row * ldc + col] = v;
                    }
                }
            }
        }
    }
}

extern "C" void kernel_launch(void* const* d_in, const int* in_sizes, int n_in,
                              void* d_out, int out_size, void* d_ws, size_t ws_size,
                              hipStream_t stream) {
    const float* x      = (const float*)d_in[0];  // (128,196,768)
    const float* k_c    = (const float*)d_in[1];  // (768,64)
    const float* v_c    = (const float*)d_in[2];  // (64,196,196)
    const float* proj_w = (const float*)d_in[3];  // (768,768)
    const float* proj_b = (const float*)d_in[4];  // (768,)
    float* out = (float*)d_out;                   // (128,196,768)

    char* ws = (char*)d_ws;
    size_t off = 0;
    auto alloc = [&](size_t bytes) {
        void* p = ws + off;
        off = (off + bytes + 255) & ~(size_t)255;
        return p;
    };
    __hip_bfloat16* x_bf  = (__hip_bfloat16*)alloc((size_t)NB * RPAD * NC * 2);   // 50.3 MB
    __hip_bfloat16* w_bf  = (__hip_bfloat16*)alloc((size_t)NC * NC * 2);          // 1.2 MB
    __hip_bfloat16* xp_t  = (__hip_bfloat16*)alloc((size_t)NB * NC * KPAD * 2);   // 44.0 MB
    __hip_bfloat16* v_pad = (__hip_bfloat16*)alloc((size_t)NB * RPAD * KPAD * 2); // 14.7 MB
    float* q    = (float*)alloc((size_t)NB * NC * 4);
    float* attn = (float*)alloc((size_t)NB * NCEN * 4);

    convert_x_kernel<<<dim3(NB, 3), 256, 0, stream>>>(x, x_bf, q);
    convert_w_kernel<<<dim3((NC * NC + 255) / 256), 256, 0, stream>>>(proj_w, w_bf);
    attn_kernel<<<dim3(NB), 256, 0, stream>>>(q, k_c, attn);
    mix_kernel<<<dim3(RPAD), 256, 0, stream>>>(attn, v_c, v_pad);

    // xp_t[b,d,m] = sum_k W[d,k] * x_bf[b,m,k]; M=768(d), N=224(m), K=768
    gemm_nt<true><<<dim3(6, 2, NB), 256, 0, stream>>>(
        w_bf, 0, x_bf, (size_t)RPAD * NC, xp_t, (size_t)NC * KPAD, nullptr,
        NC, NC, KPAD, NC, NC, KPAD);

    // out[b,n,d] = sum_m v_pad[b,n,m] * xp_t[b,d,m] + bias[d]; M=224(n), N=768(d), K=224
    gemm_nt<false><<<dim3(2, 6, NB), 256, 0, stream>>>(
        v_pad, (size_t)RPAD * KPAD, xp_t, (size_t)NC * KPAD, out, (size_t)NN * NC, proj_b,
        KPAD, KPAD, NC, KPAD, NN, NC);
}

// Round 2
// 373.267 us; speedup vs baseline: 1.1665x; 1.1665x over previous
//
#include <hip/hip_runtime.h>
#include <hip/hip_bf16.h>

// Problem: B=128, N=196, C=768, centers=64
//   q = mean_n x; attn = softmax(l2n(q)@l2n(k_c) * C^-0.5)
//   v = attn@v_c (B,N,N); out = (v @ x) @ W^T + b
// Reassociated: xp_t[b,d,m] = sum_k W[d,k] x[b,m,k]  (NT GEMM, output transposed)
//               out[b,n,d]  = sum_m v[b,n,m] xp_t[b,d,m] + bias[d] (NT GEMM)
// R2: mix_kernel parallelized over batch-groups (was 1 block/CU latency-bound);
//     gemm_nt restructured to m97 pattern: global_load_lds width=16 into
//     contiguous 128x32-short LDS tiles (no VGPR staging round-trip).

#define NB   128
#define NN   196
#define NC   768
#define NCEN 64
#define RPAD 256   // padded row-dim for x_bf (m rows) and v_pad (n rows)
#define KPAD 224   // padded K dim (m index), 7*32
#define BGRP 16    // batches per mix block

using bf16x8 = __attribute__((ext_vector_type(8))) short;
using f32x4  = __attribute__((ext_vector_type(4))) float;

__device__ __forceinline__ void async_copy16(const void* g, void* l) {
    // width=16: emits global_load_lds_dwordx4. LDS dest = wave-uniform base + lane*16.
    __builtin_amdgcn_global_load_lds((const __attribute__((address_space(1))) void*)g,
                                     (__attribute__((address_space(3))) void*)l, 16, 0, 0);
}

// ---------------- kernel 1: x -> bf16 (padded) + column means q ----------------
__global__ __launch_bounds__(256)
void convert_x_kernel(const float* __restrict__ x, __hip_bfloat16* __restrict__ x_bf,
                      float* __restrict__ q) {
    int b = blockIdx.x, chunk = blockIdx.y, t = threadIdx.x;
    int c = chunk * 256 + t;
    const float* xp = x + (size_t)b * NN * NC + c;
    __hip_bfloat16* xo = x_bf + (size_t)b * RPAD * NC + c;
    float s = 0.f;
#pragma unroll 4
    for (int m = 0; m < NN; ++m) {
        float v = xp[(size_t)m * NC];
        s += v;
        xo[(size_t)m * NC] = __float2bfloat16(v);
    }
    __hip_bfloat16 z = __float2bfloat16(0.f);
#pragma unroll 4
    for (int m = NN; m < RPAD; ++m) xo[(size_t)m * NC] = z;
    q[b * NC + c] = s * (1.0f / (float)NN);
}

// ---------------- kernel 2: proj_w -> bf16 ----------------
__global__ __launch_bounds__(256)
void convert_w_kernel(const float* __restrict__ w, __hip_bfloat16* __restrict__ w_bf) {
    int i = blockIdx.x * 256 + threadIdx.x;
    if (i < NC * NC) w_bf[i] = __float2bfloat16(w[i]);
}

// ---------------- kernel 3: attn = softmax(l2n(q) @ l2n(k_c) * scale) ----------------
__global__ __launch_bounds__(256)
void attn_kernel(const float* __restrict__ q, const float* __restrict__ k_c,
                 float* __restrict__ attn) {
    const float SCALE = 0.03608439182435161f;  // 768^-0.5
    int b = blockIdx.x, t = threadIdx.x;
    __shared__ float qs[NC];
    __shared__ float red[256];
    __shared__ float pd[4][NCEN];
    __shared__ float pk[4][NCEN];

    for (int i = t; i < NC; i += 256) qs[i] = q[b * NC + i];
    __syncthreads();

    float s = 0.f;
    for (int i = t; i < NC; i += 256) { float v = qs[i]; s += v * v; }
    red[t] = s;
    __syncthreads();
    for (int o = 128; o > 0; o >>= 1) {
        if (t < o) red[t] += red[t + o];
        __syncthreads();
    }
    float qn = sqrtf(red[0]);

    int j = t & 63, part = t >> 6;  // 4 parts x 192 c's
    float d = 0.f, kk = 0.f;
    int c0 = part * 192;
    for (int c = c0; c < c0 + 192; ++c) {
        float kv = k_c[c * NCEN + j];
        d += kv * qs[c];
        kk += kv * kv;
    }
    pd[part][j] = d;
    pk[part][j] = kk;
    __syncthreads();

    if (t < NCEN) {
        float dot = pd[0][t] + pd[1][t] + pd[2][t] + pd[3][t];
        float kn  = sqrtf(pk[0][t] + pk[1][t] + pk[2][t] + pk[3][t]);
        float lg = dot / (fmaxf(qn, 1e-12f) * fmaxf(kn, 1e-12f)) * SCALE;
        float mx = lg;
        for (int o = 32; o > 0; o >>= 1) mx = fmaxf(mx, __shfl_xor(mx, o, 64));
        float e = expf(lg - mx);
        float sum = e;
        for (int o = 32; o > 0; o >>= 1) sum += __shfl_xor(sum, o, 64);
        attn[b * NCEN + t] = e / sum;
    }
}

// ------- kernel 4: v_pad[b,n,m] = sum_c attn[b,c] v_c[c,n,m] (bf16, padded) -------
// Grid (256 n-rows, 8 batch-groups). attn staged in LDS (broadcast reads),
// v_c row cached in 64 VGPRs, reused across BGRP batches.
__global__ __launch_bounds__(256)
void mix_kernel(const float* __restrict__ attn, const float* __restrict__ v_c,
                __hip_bfloat16* __restrict__ v_pad) {
    int n = blockIdx.x;   // 0..255
    int g = blockIdx.y;   // 0..7
    int m = threadIdx.x;  // 0..255, active < 224

    __shared__ float sattn[BGRP][NCEN];
    for (int i = threadIdx.x; i < BGRP * NCEN; i += 256)
        sattn[i >> 6][i & 63] = attn[(g * BGRP + (i >> 6)) * NCEN + (i & 63)];
    __syncthreads();

    if (m >= KPAD) return;
    __hip_bfloat16 z = __float2bfloat16(0.f);
    size_t base = (size_t)n * KPAD + m;
    if (n >= NN || m >= NN) {
#pragma unroll
        for (int bb = 0; bb < BGRP; ++bb)
            v_pad[(size_t)(g * BGRP + bb) * RPAD * KPAD + base] = z;
        return;
    }
    float vc[NCEN];
    const float* vp = v_c + (size_t)n * NN + m;
#pragma unroll
    for (int c = 0; c < NCEN; ++c) vc[c] = vp[(size_t)c * NN * NN];
#pragma unroll
    for (int bb = 0; bb < BGRP; ++bb) {
        float acc = 0.f;
#pragma unroll
        for (int c = 0; c < NCEN; ++c) acc += sattn[bb][c] * vc[c];
        v_pad[(size_t)(g * BGRP + bb) * RPAD * KPAD + base] = __float2bfloat16(acc);
    }
}

// ---------------- NT GEMM: C[row,col] = sum_k A[row,k] * B[col,k] (+bias[col]) ----------------
// m97 structure: 128x128 tile, BK=32, 4 waves x (4x4) mfma_f32_16x16x32_bf16.
// LDS tiles contiguous 128 rows x 32 shorts (64 B/row); staged via
// global_load_lds width=16: lane=(row_off*4+chunk) -> LDS base+lane*16 lands at
// row (base_row+row_off), bytes [chunk*16, chunk*16+16) — exactly the tile layout.
template <bool OUT_BF16>
__global__ __launch_bounds__(256)
void gemm_nt(const __hip_bfloat16* __restrict__ A, size_t strideA,
             const __hip_bfloat16* __restrict__ Bm, size_t strideB,
             void* __restrict__ Cout, size_t strideC,
             const float* __restrict__ bias,
             int lda, int ldb, int ldc, int K, int Mstore, int Nstore) {
    int bm = blockIdx.x, bn = blockIdx.y, bb = blockIdx.z;
    const unsigned short* Ab = (const unsigned short*)A + (size_t)bb * strideA + (size_t)bm * 128 * lda;
    const unsigned short* Bb = (const unsigned short*)Bm + (size_t)bb * strideB + (size_t)bn * 128 * ldb;

    __shared__ __align__(16) unsigned short sA[128 * 32];
    __shared__ __align__(16) unsigned short sB[128 * 32];

    int tid = threadIdx.x;
    int wave = tid >> 6, lane = tid & 63;
    int wr = wave >> 1, wc = wave & 1;
    int lrow = lane & 15, quad = lane >> 4;

    // staging: each wave stages rows [wave*32, wave*32+32) of both tiles,
    // 2 instructions per operand (16 rows each).
    int row_off = lane >> 2, chunk = lane & 3;
    const unsigned short* ga0 = Ab + (size_t)(wave * 32 + row_off) * lda + chunk * 8;
    const unsigned short* ga1 = ga0 + (size_t)16 * lda;
    const unsigned short* gb0 = Bb + (size_t)(wave * 32 + row_off) * ldb + chunk * 8;
    const unsigned short* gb1 = gb0 + (size_t)16 * ldb;
    unsigned short* la0 = &sA[(wave * 32) * 32];
    unsigned short* la1 = &sA[(wave * 32 + 16) * 32];
    unsigned short* lb0 = &sB[(wave * 32) * 32];
    unsigned short* lb1 = &sB[(wave * 32 + 16) * 32];

    f32x4 acc[4][4] = {};

    for (int k0 = 0; k0 < K; k0 += 32) {
        __syncthreads();  // prev iter's LDS reads done before overwrite
        async_copy16(ga0 + k0, la0);
        async_copy16(ga1 + k0, la1);
        async_copy16(gb0 + k0, lb0);
        async_copy16(gb1 + k0, lb1);
        __syncthreads();  // compiler drains vmcnt before s_barrier

        bf16x8 af[4], bf[4];
#pragma unroll
        for (int i = 0; i < 4; ++i)
            af[i] = *(const bf16x8*)(&sA[(wr * 64 + i * 16 + lrow) * 32 + quad * 8]);
#pragma unroll
        for (int j = 0; j < 4; ++j)
            bf[j] = *(const bf16x8*)(&sB[(wc * 64 + j * 16 + lrow) * 32 + quad * 8]);
#pragma unroll
        for (int i = 0; i < 4; ++i)
#pragma unroll
            for (int j = 0; j < 4; ++j)
                acc[i][j] = __builtin_amdgcn_mfma_f32_16x16x32_bf16(af[i], bf[j], acc[i][j], 0, 0, 0);
    }

    // epilogue: D[row=(lane>>4)*4+r][col=lane&15] per 16x16 tile (m89-verified mapping)
    size_t cbase = (size_t)bb * strideC;
#pragma unroll
    for (int i = 0; i < 4; ++i) {
        int row0 = bm * 128 + wr * 64 + i * 16 + quad * 4;
#pragma unroll
        for (int j = 0; j < 4; ++j) {
            int col = bn * 128 + wc * 64 + j * 16 + lrow;
            if (col < Nstore) {
                float badd = bias ? bias[col] : 0.f;
#pragma unroll
                for (int r = 0; r < 4; ++r) {
                    int row = row0 + r;
                    if (row < Mstore) {
                        float v = acc[i][j][r] + badd;
                        if (OUT_BF16)
                            ((__hip_bfloat16*)Cout)[cbase + (size_t)row * ldc + col] = __float2bfloat16(v);
                        else
                            ((float*)Cout)[cbase + (size_t)row * ldc + col] = v;
                    }
                }
            }
        }
    }
}

extern "C" void kernel_launch(void* const* d_in, const int* in_sizes, int n_in,
                              void* d_out, int out_size, void* d_ws, size_t ws_size,
                              hipStream_t stream) {
    const float* x      = (const float*)d_in[0];  // (128,196,768)
    const float* k_c    = (const float*)d_in[1];  // (768,64)
    const float* v_c    = (const float*)d_in[2];  // (64,196,196)
    const float* proj_w = (const float*)d_in[3];  // (768,768)
    const float* proj_b = (const float*)d_in[4];  // (768,)
    float* out = (float*)d_out;                   // (128,196,768)

    char* ws = (char*)d_ws;
    size_t off = 0;
    auto alloc = [&](size_t bytes) {
        void* p = ws + off;
        off = (off + bytes + 255) & ~(size_t)255;
        return p;
    };
    __hip_bfloat16* x_bf  = (__hip_bfloat16*)alloc((size_t)NB * RPAD * NC * 2);   // 50.3 MB
    __hip_bfloat16* w_bf  = (__hip_bfloat16*)alloc((size_t)NC * NC * 2);          // 1.2 MB
    __hip_bfloat16* xp_t  = (__hip_bfloat16*)alloc((size_t)NB * NC * KPAD * 2);   // 44.0 MB
    __hip_bfloat16* v_pad = (__hip_bfloat16*)alloc((size_t)NB * RPAD * KPAD * 2); // 14.7 MB
    float* q    = (float*)alloc((size_t)NB * NC * 4);
    float* attn = (float*)alloc((size_t)NB * NCEN * 4);

    convert_x_kernel<<<dim3(NB, 3), 256, 0, stream>>>(x, x_bf, q);
    convert_w_kernel<<<dim3((NC * NC + 255) / 256), 256, 0, stream>>>(proj_w, w_bf);
    attn_kernel<<<dim3(NB), 256, 0, stream>>>(q, k_c, attn);
    mix_kernel<<<dim3(RPAD, 8), 256, 0, stream>>>(attn, v_c, v_pad);

    // xp_t[b,d,m] = sum_k W[d,k] * x_bf[b,m,k]; M=768(d), N=224(m), K=768
    gemm_nt<true><<<dim3(6, 2, NB), 256, 0, stream>>>(
        w_bf, 0, x_bf, (size_t)RPAD * NC, xp_t, (size_t)NC * KPAD, nullptr,
        NC, NC, KPAD, NC, NC, KPAD);

    // out[b,n,d] = sum_m v_pad[b,n,m] * xp_t[b,d,m] + bias[d]; M=224(n), N=768(d), K=224
    gemm_nt<false><<<dim3(2, 6, NB), 256, 0, stream>>>(
        v_pad, (size_t)RPAD * KPAD, xp_t, (size_t)NC * KPAD, out, (size_t)NN * NC, proj_b,
        KPAD, KPAD, NC, KPAD, NN, NC);
}

// Round 3
// 319.385 us; speedup vs baseline: 1.3633x; 1.1687x over previous
//
#include <hip/hip_runtime.h>
#include <hip/hip_bf16.h>

// Problem: B=128, N=196, C=768, centers=64
//   q = mean_n x; attn = softmax(l2n(q)@l2n(k_c) * C^-0.5)
//   v = attn@v_c (B,N,N); out = (v @ x) @ W^T + b
// Reassociated: xp_t[b,d,m] = sum_k W[d,k] x[b,m,k]  (NT GEMM, output transposed)
//               out[b,n,d]  = sum_m v[b,n,m] xp_t[b,d,m] + bias[d] (NT GEMM)
// R3: gemm_B uses BK=64 (32 MFMA per barrier-pair, fetch-side XOR swizzle to keep
//     ds_read_b128 at the 8-way structural floor); convert_x split 4x over rows
//     (partial q sums reduced in attn_kernel); mix BGRP=32.

#define NB   128
#define NN   196
#define NC   768
#define NCEN 64
#define RPAD 256   // padded row-dim for x_bf (m rows) and v_pad (n rows)
#define KPAD 224   // padded K dim (m index), 7*32
#define BGRP 32    // batches per mix block

using bf16x8 = __attribute__((ext_vector_type(8))) short;
using f32x4  = __attribute__((ext_vector_type(4))) float;

__device__ __forceinline__ void async_copy16(const void* g, void* l) {
    // width=16: emits global_load_lds_dwordx4. LDS dest = wave-uniform base + lane*16.
    __builtin_amdgcn_global_load_lds((const __attribute__((address_space(1))) void*)g,
                                     (__attribute__((address_space(3))) void*)l, 16, 0, 0);
}

// ---- kernel 1: x -> bf16 (padded) + partial column sums; grid (NB, 3, 4) ----
__global__ __launch_bounds__(256)
void convert_x_kernel(const float* __restrict__ x, __hip_bfloat16* __restrict__ x_bf,
                      float* __restrict__ q_part) {
    int b = blockIdx.x, chunk = blockIdx.y, part = blockIdx.z, t = threadIdx.x;
    int c = chunk * 256 + t;
    const float* xp = x + (size_t)b * NN * NC + c;
    __hip_bfloat16* xo = x_bf + (size_t)b * RPAD * NC + c;
    float s = 0.f;
    int m0 = part * 64;
#pragma unroll 4
    for (int m = m0; m < m0 + 64; ++m) {
        if (m < NN) {
            float v = xp[(size_t)m * NC];
            s += v;
            xo[(size_t)m * NC] = __float2bfloat16(v);
        } else {
            xo[(size_t)m * NC] = __float2bfloat16(0.f);
        }
    }
    q_part[((size_t)part * NB + b) * NC + c] = s;
}

// ---------------- kernel 2: proj_w -> bf16 ----------------
__global__ __launch_bounds__(256)
void convert_w_kernel(const float* __restrict__ w, __hip_bfloat16* __restrict__ w_bf) {
    int i = blockIdx.x * 256 + threadIdx.x;
    if (i < NC * NC) w_bf[i] = __float2bfloat16(w[i]);
}

// ---------------- kernel 3: attn = softmax(l2n(q) @ l2n(k_c) * scale) ----------------
__global__ __launch_bounds__(256)
void attn_kernel(const float* __restrict__ q_part, const float* __restrict__ k_c,
                 float* __restrict__ attn) {
    const float SCALE = 0.03608439182435161f;  // 768^-0.5
    int b = blockIdx.x, t = threadIdx.x;
    __shared__ float qs[NC];
    __shared__ float red[256];
    __shared__ float pd[4][NCEN];
    __shared__ float pk[4][NCEN];

    const size_t PS = (size_t)NB * NC;
    for (int i = t; i < NC; i += 256) {
        size_t idx = (size_t)b * NC + i;
        qs[i] = (q_part[idx] + q_part[PS + idx] + q_part[2 * PS + idx] + q_part[3 * PS + idx])
                * (1.0f / (float)NN);
    }
    __syncthreads();

    float s = 0.f;
    for (int i = t; i < NC; i += 256) { float v = qs[i]; s += v * v; }
    red[t] = s;
    __syncthreads();
    for (int o = 128; o > 0; o >>= 1) {
        if (t < o) red[t] += red[t + o];
        __syncthreads();
    }
    float qn = sqrtf(red[0]);

    int j = t & 63, part = t >> 6;  // 4 parts x 192 c's
    float d = 0.f, kk = 0.f;
    int c0 = part * 192;
    for (int c = c0; c < c0 + 192; ++c) {
        float kv = k_c[c * NCEN + j];
        d += kv * qs[c];
        kk += kv * kv;
    }
    pd[part][j] = d;
    pk[part][j] = kk;
    __syncthreads();

    if (t < NCEN) {
        float dot = pd[0][t] + pd[1][t] + pd[2][t] + pd[3][t];
        float kn  = sqrtf(pk[0][t] + pk[1][t] + pk[2][t] + pk[3][t]);
        float lg = dot / (fmaxf(qn, 1e-12f) * fmaxf(kn, 1e-12f)) * SCALE;
        float mx = lg;
        for (int o = 32; o > 0; o >>= 1) mx = fmaxf(mx, __shfl_xor(mx, o, 64));
        float e = expf(lg - mx);
        float sum = e;
        for (int o = 32; o > 0; o >>= 1) sum += __shfl_xor(sum, o, 64);
        attn[b * NCEN + t] = e / sum;
    }
}

// ------- kernel 4: v_pad[b,n,m] = sum_c attn[b,c] v_c[c,n,m]; grid (RPAD, NB/BGRP) -------
__global__ __launch_bounds__(256)
void mix_kernel(const float* __restrict__ attn, const float* __restrict__ v_c,
                __hip_bfloat16* __restrict__ v_pad) {
    int n = blockIdx.x;   // 0..255
    int g = blockIdx.y;   // 0..3
    int m = threadIdx.x;  // 0..255, active < 224

    __shared__ float sattn[BGRP][NCEN];
    for (int i = threadIdx.x; i < BGRP * NCEN; i += 256)
        sattn[i >> 6][i & 63] = attn[(g * BGRP + (i >> 6)) * NCEN + (i & 63)];
    __syncthreads();

    if (m >= KPAD) return;
    __hip_bfloat16 z = __float2bfloat16(0.f);
    size_t base = (size_t)n * KPAD + m;
    if (n >= NN || m >= NN) {
#pragma unroll
        for (int bb = 0; bb < BGRP; ++bb)
            v_pad[(size_t)(g * BGRP + bb) * RPAD * KPAD + base] = z;
        return;
    }
    float vc[NCEN];
    const float* vp = v_c + (size_t)n * NN + m;
#pragma unroll
    for (int c = 0; c < NCEN; ++c) vc[c] = vp[(size_t)c * NN * NN];
#pragma unroll
    for (int bb = 0; bb < BGRP; ++bb) {
        float acc = 0.f;
#pragma unroll
        for (int c = 0; c < NCEN; ++c) acc += sattn[bb][c] * vc[c];
        v_pad[(size_t)(g * BGRP + bb) * RPAD * KPAD + base] = __float2bfloat16(acc);
    }
}

// ---------------- NT GEMM: C[row,col] = sum_k A[row,k] * B[col,k] (+bias[col]) ----------------
// 128x128 tile, 4 waves x (4x4) mfma_f32_16x16x32_bf16, global_load_lds width=16.
// BK=64: row = 128 B = exactly 32 banks, so logical chunks are XOR-swizzled by row&7
// on the FETCH side (global_load_lds can't scatter); fragment reads invert the swizzle.
// This keeps ds_read_b128 at its 8-lanes-per-bank-group structural floor.
// BK=32: row = 64 B, row-parity already splits bank groups — no swizzle (m97 layout).
template <int BK, bool OUT_BF16>
__global__ __launch_bounds__(256)
void gemm_nt(const __hip_bfloat16* __restrict__ A, size_t strideA,
             const __hip_bfloat16* __restrict__ Bm, size_t strideB,
             void* __restrict__ Cout, size_t strideC,
             const float* __restrict__ bias,
             int lda, int ldb, int ldc, int K, int Mstore, int Nstore) {
    int bm = blockIdx.x, bn = blockIdx.y, bb = blockIdx.z;
    const unsigned short* Ab = (const unsigned short*)A + (size_t)bb * strideA + (size_t)bm * 128 * lda;
    const unsigned short* Bb = (const unsigned short*)Bm + (size_t)bb * strideB + (size_t)bn * 128 * ldb;

    __shared__ __align__(16) unsigned short sA[128 * BK];
    __shared__ __align__(16) unsigned short sB[128 * BK];

    int tid = threadIdx.x;
    int wave = tid >> 6, lane = tid & 63;
    int wr = wave >> 1, wc = wave & 1;
    int lrow = lane & 15, quad = lane >> 4;

    // staging: each wave stages rows [wave*32, wave*32+32) of both tiles.
    constexpr int CH  = BK / 8;   // 16B chunks per row (8 @ BK64, 4 @ BK32)
    constexpr int RPI = 64 / CH;  // rows per instruction (8 @ BK64, 16 @ BK32)
    constexpr int NI  = 32 / RPI; // instructions per tile per wave (4 / 2)
    int srow = lane / CH;
    int sc   = lane % CH;                                  // physical chunk written
    int lc   = (BK == 64) ? (sc ^ (srow & 7)) : sc;        // logical chunk fetched

    const unsigned short* ga[NI];
    const unsigned short* gb[NI];
    unsigned short* la[NI];
    unsigned short* lb[NI];
#pragma unroll
    for (int i = 0; i < NI; ++i) {
        int row = wave * 32 + i * RPI + srow;
        ga[i] = Ab + (size_t)row * lda + lc * 8;
        gb[i] = Bb + (size_t)row * ldb + lc * 8;
        la[i] = &sA[(wave * 32 + i * RPI) * BK];
        lb[i] = &sB[(wave * 32 + i * RPI) * BK];
    }

    f32x4 acc[4][4] = {};

    for (int k0 = 0; k0 < K; k0 += BK) {
        __syncthreads();  // prev iter's LDS reads done before overwrite
#pragma unroll
        for (int i = 0; i < NI; ++i) async_copy16(ga[i] + k0, la[i]);
#pragma unroll
        for (int i = 0; i < NI; ++i) async_copy16(gb[i] + k0, lb[i]);
        __syncthreads();  // compiler drains vmcnt before s_barrier

#pragma unroll
        for (int kh = 0; kh < BK / 32; ++kh) {
            int pcbase = (BK == 64) ? ((kh * 4 + quad) ^ (lrow & 7)) : quad;
            bf16x8 af[4], bfr[4];
#pragma unroll
            for (int i = 0; i < 4; ++i)
                af[i] = *(const bf16x8*)(&sA[(wr * 64 + i * 16 + lrow) * BK + pcbase * 8]);
#pragma unroll
            for (int j = 0; j < 4; ++j)
                bfr[j] = *(const bf16x8*)(&sB[(wc * 64 + j * 16 + lrow) * BK + pcbase * 8]);
#pragma unroll
            for (int i = 0; i < 4; ++i)
#pragma unroll
                for (int j = 0; j < 4; ++j)
                    acc[i][j] = __builtin_amdgcn_mfma_f32_16x16x32_bf16(af[i], bfr[j], acc[i][j], 0, 0, 0);
        }
    }

    // epilogue: D[row=(lane>>4)*4+r][col=lane&15] per 16x16 tile (m89-verified mapping)
    size_t cbase = (size_t)bb * strideC;
#pragma unroll
    for (int i = 0; i < 4; ++i) {
        int row0 = bm * 128 + wr * 64 + i * 16 + quad * 4;
#pragma unroll
        for (int j = 0; j < 4; ++j) {
            int col = bn * 128 + wc * 64 + j * 16 + lrow;
            if (col < Nstore) {
                float badd = bias ? bias[col] : 0.f;
#pragma unroll
                for (int r = 0; r < 4; ++r) {
                    int row = row0 + r;
                    if (row < Mstore) {
                        float v = acc[i][j][r] + badd;
                        if (OUT_BF16)
                            ((__hip_bfloat16*)Cout)[cbase + (size_t)row * ldc + col] = __float2bfloat16(v);
                        else
                            ((float*)Cout)[cbase + (size_t)row * ldc + col] = v;
                    }
                }
            }
        }
    }
}

extern "C" void kernel_launch(void* const* d_in, const int* in_sizes, int n_in,
                              void* d_out, int out_size, void* d_ws, size_t ws_size,
                              hipStream_t stream) {
    const float* x      = (const float*)d_in[0];  // (128,196,768)
    const float* k_c    = (const float*)d_in[1];  // (768,64)
    const float* v_c    = (const float*)d_in[2];  // (64,196,196)
    const float* proj_w = (const float*)d_in[3];  // (768,768)
    const float* proj_b = (const float*)d_in[4];  // (768,)
    float* out = (float*)d_out;                   // (128,196,768)

    char* ws = (char*)d_ws;
    size_t off = 0;
    auto alloc = [&](size_t bytes) {
        void* p = ws + off;
        off = (off + bytes + 255) & ~(size_t)255;
        return p;
    };
    __hip_bfloat16* x_bf  = (__hip_bfloat16*)alloc((size_t)NB * RPAD * NC * 2);   // 50.3 MB
    __hip_bfloat16* w_bf  = (__hip_bfloat16*)alloc((size_t)NC * NC * 2);          // 1.2 MB
    __hip_bfloat16* xp_t  = (__hip_bfloat16*)alloc((size_t)NB * NC * KPAD * 2);   // 44.0 MB
    __hip_bfloat16* v_pad = (__hip_bfloat16*)alloc((size_t)NB * RPAD * KPAD * 2); // 14.7 MB
    float* q_part = (float*)alloc((size_t)4 * NB * NC * 4);                       // 1.6 MB
    float* attn   = (float*)alloc((size_t)NB * NCEN * 4);

    convert_x_kernel<<<dim3(NB, 3, 4), 256, 0, stream>>>(x, x_bf, q_part);
    convert_w_kernel<<<dim3((NC * NC + 255) / 256), 256, 0, stream>>>(proj_w, w_bf);
    attn_kernel<<<dim3(NB), 256, 0, stream>>>(q_part, k_c, attn);
    mix_kernel<<<dim3(RPAD, NB / BGRP), 256, 0, stream>>>(attn, v_c, v_pad);

    // xp_t[b,d,m] = sum_k W[d,k] * x_bf[b,m,k]; M=768(d), N=224(m), K=768, BK=64
    gemm_nt<64, true><<<dim3(6, 2, NB), 256, 0, stream>>>(
        w_bf, 0, x_bf, (size_t)RPAD * NC, xp_t, (size_t)NC * KPAD, nullptr,
        NC, NC, KPAD, NC, NC, KPAD);

    // out[b,n,d] = sum_m v_pad[b,n,m] * xp_t[b,d,m] + bias[d]; M=224(n), N=768(d), K=224, BK=32
    gemm_nt<32, false><<<dim3(2, 6, NB), 256, 0, stream>>>(
        v_pad, (size_t)RPAD * KPAD, xp_t, (size_t)NC * KPAD, out, (size_t)NN * NC, proj_b,
        KPAD, KPAD, NC, KPAD, NN, NC);
}